// Round 14
// baseline (4754.200 us; speedup 1.0000x reference)
//
#include <hip/hip_runtime.h>
#include <hip/hip_bf16.h>
#include <stdint.h>

typedef __bf16 bf16;
typedef __attribute__((ext_vector_type(8))) __bf16 bf16x8;
typedef __attribute__((ext_vector_type(4))) float f32x4;
typedef __attribute__((ext_vector_type(2))) unsigned int u32x2;
typedef unsigned long long u64;

#define MFMA_B16(a,b,c) __builtin_amdgcn_mfma_f32_16x16x32_bf16((a),(b),(c),0,0,0)

// problem dims
#define BATCH  1024
#define NSTEPS 1024
#define OBS    32
#define ACTD   8
#define WIDTH  512
#define ROWS   16
#define OUTS   ((NSTEPS+1)*OBS)
#define K0     128   // [y_hi 32 | y_lo 32 | act 8 | one@72 | zero-pad -> 128]

// ws layout (bf16 element offsets)
#define W0P_OFF 0
#define W0P_N   (WIDTH*K0)
#define W1_OFF  (W0P_OFF + W0P_N)
#define WBIG_N  (WIDTH*WIDTH)
#define W2_OFF  (W1_OFF + WBIG_N)
#define W3_OFF  (W2_OFF + WBIG_N)
#define W3_N    (OBS*WIDTH)
#define TAU_OFF (W3_OFF + W3_N)
// mailboxes: 64 groups x 3 hop-slots x 4 members x 4KB (slot1 unused)
#define MB_OFF  606720
#define MB_N    (64*3*4*2048)
#define FLAG_DW_IDX (((MB_OFF + MB_N)/2) + 64)
#define NFLAG   (64*3*4*16)

#define ALF(P)   __hip_atomic_load((P),  __ATOMIC_RELAXED, __HIP_MEMORY_SCOPE_AGENT)
#define ASF(P,V) __hip_atomic_store((P), (V), __ATOMIC_RELAXED, __HIP_MEMORY_SCOPE_AGENT)

#define LBAR() do{ asm volatile("s_waitcnt lgkmcnt(0)" ::: "memory"); \
                   __builtin_amdgcn_s_barrier(); \
                   __builtin_amdgcn_sched_barrier(0); }while(0)
#define FBAR() do{ asm volatile("s_waitcnt vmcnt(0) lgkmcnt(0)" ::: "memory"); \
                   __builtin_amdgcn_s_barrier(); \
                   __builtin_amdgcn_sched_barrier(0); }while(0)

__global__ void setup_kernel(const float* __restrict__ W0, const float* __restrict__ b0r,
                             const float* __restrict__ W1, const float* __restrict__ W2,
                             const float* __restrict__ W3,
                             const int* __restrict__ tau, bf16* __restrict__ wsb){
  int i = blockIdx.x*blockDim.x + threadIdx.x;
  int stride = gridDim.x*blockDim.x;
  for (int idx=i; idx<W0P_N; idx+=stride){
    int r = idx >> 7, c = idx & 127;
    float v = 0.0f;
    if (c < 32)       v = W0[r*40 + c];
    else if (c < 64)  v = W0[r*40 + (c-32)];
    else if (c < 72)  v = W0[r*40 + 32 + (c-64)];
    else if (c == 72) v = b0r[r];
    wsb[W0P_OFF+idx] = (bf16)v;
  }
  for (int idx=i; idx<WBIG_N; idx+=stride) wsb[W1_OFF+idx] = (bf16)W1[idx];
  for (int idx=i; idx<WBIG_N; idx+=stride) wsb[W2_OFF+idx] = (bf16)W2[idx];
  for (int idx=i; idx<W3_N;  idx+=stride) wsb[W3_OFF+idx] = (bf16)W3[idx];
  int* flags = ((int*)wsb) + FLAG_DW_IDX;
  for (int idx=i; idx<NFLAG; idx+=stride) flags[idx] = 0;
  if (i==0){
    int ti = *tau;
    float tf;
    if (ti >= -1000000 && ti <= 1000000) tf = (float)ti;
    else { union {int q; float f;} u; u.q = ti; tf = u.f; }
    *(float*)(wsb + TAU_OFF) = tf;
  }
}

__device__ __forceinline__ float leaky(float v){ return v < 0.0f ? 0.01f*v : v; }

__device__ __forceinline__ uint32_t pk2(float a, float b){
  union { bf16 h; uint16_t u; } ua, ub; ua.h = (bf16)a; ub.h = (bf16)b;
  return (uint32_t)ua.u | ((uint32_t)ub.u << 16);
}

__global__ __launch_bounds__(512, 2)
void ode_kernel(const float* __restrict__ init_obs, const float* __restrict__ actions,
                const float* __restrict__ b1g, const float* __restrict__ b2g,
                const float* __restrict__ b3g,
                bf16* __restrict__ wsrw, float* __restrict__ out){
  const bf16* w0g = wsrw + W0P_OFF;
  const bf16* w1g = wsrw + W1_OFF;
  const bf16* w2g = wsrw + W2_OFF;
  const bf16* w3g = wsrw + W3_OFF;
  u64* mbq = (u64*)(wsrw + MB_OFF);
  float* mbf = (float*)(wsrw + MB_OFF);
  int* flags = ((int*)wsrw) + FLAG_DW_IDX;
  const float tauf = *(const float*)(wsrw + TAU_OFF);

  __shared__ alignas(16) bf16 w0s[96*512];     // 96KB full W0, fragment order (3 k-steps)
  __shared__ alignas(16) bf16 w3s[8*512];      // 8KB  W3 own-K slices (nt*4+q order)
  __shared__ alignas(16) bf16 hF0[ROWS*WIDTH]; // 16KB h0 / h2
  __shared__ alignas(16) bf16 hF1[ROWS*WIDTH]; // 16KB h1 (own + gathered)
  __shared__ alignas(16) bf16 xin[ROWS*K0];    // 4KB
  __shared__ int sdead;

  const int t    = threadIdx.x;
  const int lane = t & 63;
  const int wave = t >> 6;
  const int fm   = lane & 15;
  const int fk   = lane >> 4;
  const int b    = blockIdx.x;
  const int xcd  = b & 7, slot = b >> 3;
  const int g    = xcd*8 + (slot >> 2);   // group 0..63 (members share XCD heuristic)
  const int j    = slot & 3;              // member: out-col quarter
  const int gb0  = g * ROWS;
  const int pm0 = (j==0)?1:0, pm1 = (j<2)?2:1, pm2 = (j<3)?3:2;

  const int hbase1 = fm*WIDTH + ((fk*8) ^ (fm*8));
  const int xbase0 = fm*K0    + ((fk*8) ^ (fm*8));
  const int chi    = j*128 + wave*16 + fk*4;

  const f32x4 b1q = *(const f32x4*)&b1g[chi];
  const f32x4 b2q = *(const f32x4*)&b2g[chi];

  // ---- resident weights: W1/W2 quarter -> regs (AGPR side), pinned ----
  bf16x8 w1f[16], w2f[16];
  {
    const bf16* p1 = w1g + (size_t)(j*128 + wave*16 + fm)*WIDTH + fk*8;
    const bf16* p2 = w2g + (size_t)(j*128 + wave*16 + fm)*WIDTH + fk*8;
    #pragma unroll
    for (int kk=0; kk<16; kk++) w1f[kk] = *(const bf16x8*)(p1 + kk*32);
    #pragma unroll
    for (int kk=0; kk<16; kk++) w2f[kk] = *(const bf16x8*)(p2 + kk*32);
  }
  // ---- FULL W0 (3 k-steps) + own W3 K-slices -> LDS, fragment order ----
  {
    #pragma unroll
    for (int n=0; n<4; n++){
      const bf16* s0 = w0g + (size_t)((wave*4+n)*16 + fm)*K0 + fk*8;
      #pragma unroll
      for (int k=0; k<3; k++){
        bf16x8 v = *(const bf16x8*)(s0 + k*32);
        *(bf16x8*)&w0s[((wave*4+n)*3 + k)*512 + lane*8] = v;
      }
    }
    // slot w holds (nt = w>>2, q = w&3): A-frag = W3[nt*16+fm][j*128 + q*32 + fk*8 ..]
    const int nt_ = wave >> 2, q_ = wave & 3;
    bf16x8 v3 = *(const bf16x8*)(w3g + (size_t)(nt_*16 + fm)*WIDTH + j*128 + q_*32 + fk*8);
    *(bf16x8*)&w3s[wave*512 + lane*8] = v3;
  }

  // update-phase constants
  const int urow = t >> 5, ucol = t & 31;
  const float b3v = b3g[ucol];
  float* const outp = out + (size_t)(gb0 + urow)*OUTS + ucol;
  const int arow = (t >> 3) & 15, acol = t & 7;
  const float* const actp = actions + (size_t)(gb0 + arow)*(NSTEPS*ACTD) + acol;
  const int swU    = (urow & 15) << 3;
  const int xin_yh = urow*K0 + (ucol ^ swU);
  const int xin_yl = urow*K0 + ((ucol + 32) ^ swU);
  const int xin_ac = arow*K0 + ((64 + acol) ^ ((arow & 15) << 3));

  // ---- init state (y kept in per-thread register) ----
  float yreg;
  {
    if (t == 0) sdead = 0;
    #pragma unroll
    for (int q=0; q<(ROWS*K0)/512; q++) xin[q*512 + t] = (bf16)0.0f;
    __syncthreads();
    yreg = init_obs[(gb0 + urow)*OBS + ucol];
    if (j == 0) outp[0] = yreg;
    bf16 yh = (bf16)yreg;
    xin[xin_yh] = yh;
    xin[xin_yl] = (bf16)(yreg - (float)yh);
    if (t < 128) xin[xin_ac] = (bf16)actp[0];
    if (t < 16)  xin[t*K0 + (72 ^ ((t&15)*8))] = (bf16)1.0f;
  }
  __syncthreads();

  // pin resident weights (244 regs total = 2 waves/SIMD; do not add register state)
  #pragma unroll
  for (int kk=0; kk<16; kk++){ asm volatile("" : "+v"(w1f[kk])); }
  #pragma unroll
  for (int kk=0; kk<16; kk++){ asm volatile("" : "+v"(w2f[kk])); }

  #define STORE_OWN01(ACC, BQ, HF, HOP) do{ \
    float r0_ = leaky((ACC)[0] + (BQ)[0]); \
    float r1_ = leaky((ACC)[1] + (BQ)[1]); \
    float r2_ = leaky((ACC)[2] + (BQ)[2]); \
    float r3_ = leaky((ACC)[3] + (BQ)[3]); \
    union { u32x2 v; u64 q; } pu_; \
    pu_.v = (u32x2){ pk2(r0_, r1_), pk2(r2_, r3_) }; \
    *(u32x2*)&HF[fm*WIDTH + (chi ^ (fm*8))] = pu_.v; \
    __hip_atomic_store(mbq + (size_t)((g*3+(HOP))*4 + j)*512 + fm*32 + wave*4 + fk, \
                       pu_.q, __ATOMIC_RELAXED, __HIP_MEMORY_SCOPE_AGENT); \
  }while(0)

  #define SYNC_HOP(HOP, ST1) do{ \
    FBAR(); \
    if (t == 0) __hip_atomic_store(flags + ((g*3+(HOP))*4 + j)*16, (ST1), \
                                   __ATOMIC_RELAXED, __HIP_MEMORY_SCOPE_AGENT); \
    if (wave == 0 && lane < 3){ \
      int pm_ = (lane==0)?pm0:((lane==1)?pm1:pm2); \
      const int* fp_ = flags + ((g*3+(HOP))*4 + pm_)*16; \
      int cnt_ = 0; \
      while (!*(volatile int*)&sdead && \
             __hip_atomic_load(fp_, __ATOMIC_RELAXED, __HIP_MEMORY_SCOPE_AGENT) < (ST1)){ \
        __builtin_amdgcn_s_sleep(1); \
        if (++cnt_ > (1<<20)) { *(volatile int*)&sdead = 1; break; } \
      } \
    } \
    LBAR(); \
  }while(0)

  #define GATHER01(HOP, DST) do{ \
    const int br_ = t >> 5, cg_ = t & 31; \
    const size_t hb_ = (size_t)((g*3+(HOP))*4); \
    u64 v0_ = __hip_atomic_load(mbq + (hb_+pm0)*512 + br_*32 + cg_, \
                                 __ATOMIC_RELAXED, __HIP_MEMORY_SCOPE_AGENT); \
    u64 v1_ = __hip_atomic_load(mbq + (hb_+pm1)*512 + br_*32 + cg_, \
                                 __ATOMIC_RELAXED, __HIP_MEMORY_SCOPE_AGENT); \
    u64 v2_ = __hip_atomic_load(mbq + (hb_+pm2)*512 + br_*32 + cg_, \
                                 __ATOMIC_RELAXED, __HIP_MEMORY_SCOPE_AGENT); \
    *(u64*)&DST[br_*WIDTH + ((pm0*128 + cg_*4) ^ (br_*8))] = v0_; \
    *(u64*)&DST[br_*WIDTH + ((pm1*128 + cg_*4) ^ (br_*8))] = v1_; \
    *(u64*)&DST[br_*WIDTH + ((pm2*128 + cg_*4) ^ (br_*8))] = v2_; \
    LBAR(); \
  }while(0)

  #define L2Q(Q) do{ \
    _Pragma("unroll") \
    for (int kk=(Q)*4; kk<(Q)*4+4; kk++){ \
      bf16x8 bb = *(const bf16x8*)&hF1[hbase1 ^ (kk*32)]; \
      acc2 = MFMA_B16(w2f[kk], bb, acc2); \
    } \
  }while(0)

  #define L2MID() do{ \
    if (wave == 0 && lane < 3){ \
      int pm_ = (lane==0)?pm0:((lane==1)?pm1:pm2); \
      const int* fp_ = flags + ((g*3+0)*4 + pm_)*16; \
      int cnt_ = 0; \
      while (!*(volatile int*)&sdead && \
             __hip_atomic_load(fp_, __ATOMIC_RELAXED, __HIP_MEMORY_SCOPE_AGENT) < st1){ \
        __builtin_amdgcn_s_sleep(1); \
        if (++cnt_ > (1<<20)) { *(volatile int*)&sdead = 1; break; } \
      } \
    } \
    LBAR(); \
    GATHER01(0, hF1); \
  }while(0)

  const f32x4 z4 = {0,0,0,0};

  for (int s=0; s<NSTEPS; ++s){
    const int st1 = s + 1;
    const int sidx = (st1 < NSTEPS) ? st1 : 0;
    float av = actp[(size_t)sidx*ACTD];

    // ---- l0 (replicated, full 512 cols): xin @ W0^T, local only ----
    {
      #pragma unroll
      for (int n=0; n<4; n++){
        f32x4 acc = {0,0,0,0};
        #pragma unroll
        for (int k=0; k<3; k++){
          bf16x8 a  = *(const bf16x8*)&w0s[((wave*4+n)*3 + k)*512 + lane*8];
          bf16x8 bb = *(const bf16x8*)&xin[xbase0 ^ (k*32)];
          acc = MFMA_B16(a, bb, acc);
        }
        int ob = (wave*4+n)*16 + fk*4;
        u32x2 pw = { pk2(leaky(acc[0]), leaky(acc[1])),
                     pk2(leaky(acc[2]), leaky(acc[3])) };
        *(u32x2*)&hF0[fm*WIDTH + (ob ^ (fm*8))] = pw;
      }
    }
    LBAR();
    // a(s+1) write: l0(s) has read xin; next xin read is l0(s+1)
    if (t < 128) xin[xin_ac] = (bf16)av;

    // ---- l1: hF0(full h0) @ W1q^T -> own 128 cols, publish (hop 0) ----
    {
      f32x4 acc = {0,0,0,0};
      #pragma unroll
      for (int kk=0; kk<16; kk++){
        bf16x8 bb = *(const bf16x8*)&hF0[hbase1 ^ (kk*32)];
        acc = MFMA_B16(w1f[kk], bb, acc);
      }
      STORE_OWN01(acc, b1q, hF1, 0);
    }
    FBAR();
    if (t == 0) __hip_atomic_store(flags + ((g*3+0)*4 + j)*16, st1,
                                   __ATOMIC_RELAXED, __HIP_MEMORY_SCOPE_AGENT);

    // ---- l2: own-K quarter first (overlaps peers' flag+gather), then rest ----
    f32x4 acc2 = {0,0,0,0};
    switch (j){
      case 0:  L2Q(0); L2MID(); L2Q(1); L2Q(2); L2Q(3); break;
      case 1:  L2Q(1); L2MID(); L2Q(0); L2Q(2); L2Q(3); break;
      case 2:  L2Q(2); L2MID(); L2Q(0); L2Q(1); L2Q(3); break;
      default: L2Q(3); L2MID(); L2Q(0); L2Q(1); L2Q(2); break;
    }
    {
      u32x2 pw = { pk2(leaky(acc2[0]+b2q[0]), leaky(acc2[1]+b2q[1])),
                   pk2(leaky(acc2[2]+b2q[2]), leaky(acc2[3]+b2q[3])) };
      *(u32x2*)&hF0[fm*WIDTH + (chi ^ (fm*8))] = pw;
    }
    LBAR();

    // ---- l3: chained MFMA over own 4 K-chunks (x4 redundant); publish from
    //      waves 0,4 straight from registers (no pr LDS round-trip/reduce) ----
    {
      const int nt = wave >> 2;        // obs col block 0..1
      f32x4 a3 = z4;
      #pragma unroll
      for (int q=0; q<4; q++){
        bf16x8 a  = *(const bf16x8*)&w3s[((nt<<2)+q)*512 + lane*8];
        bf16x8 bb = *(const bf16x8*)&hF0[fm*WIDTH + ((j*128 + q*32 + fk*8) ^ (fm*8))];
        a3 = MFMA_B16(a, bb, a3);
      }
      if ((wave & 3) == 0){
        // lane holds dy-partials for batch=fm, obs cols nt*16 + fk*4 .. +3
        float* dp = mbf + (size_t)((g*3+2)*4 + j)*1024 + fm*32 + nt*16 + fk*4;
        #pragma unroll
        for (int r=0; r<4; r++) ASF(dp + r, a3[r]);
      }
    }
    SYNC_HOP(2, st1);

    // ---- update: 4-slot fixed-order sum -> Euler -> emit -> reseed ----
    {
      const size_t db = (size_t)((g*3+2)*4)*1024 + urow*32 + ucol;
      float v0 = ALF(mbf + db + 0*1024);
      float v1 = ALF(mbf + db + 1*1024);
      float v2 = ALF(mbf + db + 2*1024);
      float v3 = ALF(mbf + db + 3*1024);
      float dy = b3v + v0 + v1 + v2 + v3;
      float yn = yreg + tauf * dy;
      yreg = yn;
      if (j == 0) outp[(size_t)st1*OBS] = yn;
      bf16 yh = (bf16)yn;
      xin[xin_yh] = yh;
      xin[xin_yl] = (bf16)(yn - (float)yh);
    }
    LBAR();
  }
  asm volatile("s_waitcnt vmcnt(0) lgkmcnt(0)" ::: "memory");
}

extern "C" void kernel_launch(void* const* d_in, const int* in_sizes, int n_in,
                              void* d_out, int out_size, void* d_ws, size_t ws_size,
                              hipStream_t stream){
  const float* init_obs = (const float*)d_in[0];
  const float* actions  = (const float*)d_in[1];
  const float* W0 = (const float*)d_in[2];
  const float* b0 = (const float*)d_in[3];
  const float* W1 = (const float*)d_in[4];
  const float* b1 = (const float*)d_in[5];
  const float* W2 = (const float*)d_in[6];
  const float* b2 = (const float*)d_in[7];
  const float* W3 = (const float*)d_in[8];
  const float* b3 = (const float*)d_in[9];
  const int*  tau = (const int*)d_in[10];
  bf16* wsb = (bf16*)d_ws;
  float* out = (float*)d_out;

  hipLaunchKernelGGL(setup_kernel, dim3(512), dim3(256), 0, stream,
                     W0, b0, W1, W2, W3, tau, wsb);
  hipLaunchKernelGGL(ode_kernel, dim3(256), dim3(512), 0, stream,
                     init_obs, actions, b1, b2, b3, wsb, out);
}

// Round 15
// 4589.100 us; speedup vs baseline: 1.0360x; 1.0360x over previous
//
#include <hip/hip_runtime.h>
#include <hip/hip_bf16.h>
#include <stdint.h>

typedef __bf16 bf16;
typedef __attribute__((ext_vector_type(8))) __bf16 bf16x8;
typedef __attribute__((ext_vector_type(4))) float f32x4;
typedef __attribute__((ext_vector_type(2))) unsigned int u32x2;
typedef unsigned long long u64;

#define MFMA_B16(a,b,c) __builtin_amdgcn_mfma_f32_16x16x32_bf16((a),(b),(c),0,0,0)

// problem dims
#define BATCH  1024
#define NSTEPS 1024
#define OBS    32
#define ACTD   8
#define WIDTH  512
#define ROWS   16
#define OUTS   ((NSTEPS+1)*OBS)
#define K0     128   // [y_hi 32 | y_lo 32 | act 8 | one@72 | zero-pad -> 128]

// ws layout (bf16 element offsets)
#define W0P_OFF 0
#define W0P_N   (WIDTH*K0)
#define W1_OFF  (W0P_OFF + W0P_N)
#define WBIG_N  (WIDTH*WIDTH)
#define W2_OFF  (W1_OFF + WBIG_N)
#define W3_OFF  (W2_OFF + WBIG_N)
#define W3_N    (OBS*WIDTH)
#define TAU_OFF (W3_OFF + W3_N)
// mailboxes: 64 groups x 3 hop-slots x 4 members x 4KB (slot1 unused)
#define MB_OFF  606720
#define MB_N    (64*3*4*2048)
#define FLAG_DW_IDX (((MB_OFF + MB_N)/2) + 64)
#define NFLAG   (64*3*4*16)

#define LBAR() do{ asm volatile("s_waitcnt lgkmcnt(0)" ::: "memory"); \
                   __builtin_amdgcn_s_barrier(); \
                   __builtin_amdgcn_sched_barrier(0); }while(0)
#define FBAR() do{ asm volatile("s_waitcnt vmcnt(0) lgkmcnt(0)" ::: "memory"); \
                   __builtin_amdgcn_s_barrier(); \
                   __builtin_amdgcn_sched_barrier(0); }while(0)

__global__ void setup_kernel(const float* __restrict__ W0, const float* __restrict__ b0r,
                             const float* __restrict__ W1, const float* __restrict__ W2,
                             const float* __restrict__ W3,
                             const int* __restrict__ tau, bf16* __restrict__ wsb){
  int i = blockIdx.x*blockDim.x + threadIdx.x;
  int stride = gridDim.x*blockDim.x;
  for (int idx=i; idx<W0P_N; idx+=stride){
    int r = idx >> 7, c = idx & 127;
    float v = 0.0f;
    if (c < 32)       v = W0[r*40 + c];
    else if (c < 64)  v = W0[r*40 + (c-32)];
    else if (c < 72)  v = W0[r*40 + 32 + (c-64)];
    else if (c == 72) v = b0r[r];
    wsb[W0P_OFF+idx] = (bf16)v;
  }
  for (int idx=i; idx<WBIG_N; idx+=stride) wsb[W1_OFF+idx] = (bf16)W1[idx];
  for (int idx=i; idx<WBIG_N; idx+=stride) wsb[W2_OFF+idx] = (bf16)W2[idx];
  for (int idx=i; idx<W3_N;  idx+=stride) wsb[W3_OFF+idx] = (bf16)W3[idx];
  int* flags = ((int*)wsb) + FLAG_DW_IDX;
  for (int idx=i; idx<NFLAG; idx+=stride) flags[idx] = 0;
  if (i==0){
    int ti = *tau;
    float tf;
    if (ti >= -1000000 && ti <= 1000000) tf = (float)ti;
    else { union {int q; float f;} u; u.q = ti; tf = u.f; }
    *(float*)(wsb + TAU_OFF) = tf;
  }
}

__device__ __forceinline__ float leaky(float v){ return v < 0.0f ? 0.01f*v : v; }

__device__ __forceinline__ uint32_t pk2(float a, float b){
  union { bf16 h; uint16_t u; } ua, ub; ua.h = (bf16)a; ub.h = (bf16)b;
  return (uint32_t)ua.u | ((uint32_t)ub.u << 16);
}

__global__ __launch_bounds__(512, 2)
void ode_kernel(const float* __restrict__ init_obs, const float* __restrict__ actions,
                const float* __restrict__ b1g, const float* __restrict__ b2g,
                const float* __restrict__ b3g,
                bf16* __restrict__ wsrw, float* __restrict__ out){
  const bf16* w0g = wsrw + W0P_OFF;
  const bf16* w1g = wsrw + W1_OFF;
  const bf16* w2g = wsrw + W2_OFF;
  const bf16* w3g = wsrw + W3_OFF;
  u64* mbq = (u64*)(wsrw + MB_OFF);
  float* mbf = (float*)(wsrw + MB_OFF);
  int* flags = ((int*)wsrw) + FLAG_DW_IDX;
  const float tauf = *(const float*)(wsrw + TAU_OFF);

  __shared__ alignas(16) bf16 w0s[96*512];     // 96KB full W0, fragment order (3 k-steps)
  __shared__ alignas(16) bf16 w3s[8*512];      // 8KB  W3 own-K slice
  __shared__ alignas(16) bf16 hF0[ROWS*WIDTH]; // 16KB h0 / h2
  __shared__ alignas(16) bf16 hF1[ROWS*WIDTH]; // 16KB h1 (own + gathered)
  __shared__ alignas(16) bf16 xin[ROWS*K0];    // 4KB
  __shared__ alignas(16) float pr[8][16][20];  // 10KB l3 partials
  __shared__ int sdead;

  const int t    = threadIdx.x;
  const int lane = t & 63;
  const int wave = t >> 6;
  const int fm   = lane & 15;
  const int fk   = lane >> 4;
  const int b    = blockIdx.x;
  const int xcd  = b & 7, slot = b >> 3;
  const int g    = xcd*8 + (slot >> 2);   // group 0..63 (members share XCD heuristic)
  const int j    = slot & 3;              // member: out-col quarter
  const int gb0  = g * ROWS;
  const int pm0 = (j==0)?1:0, pm1 = (j<2)?2:1, pm2 = (j<3)?3:2;

  const int hbase1 = fm*WIDTH + ((fk*8) ^ (fm*8));
  const int xbase0 = fm*K0    + ((fk*8) ^ (fm*8));
  const int chi    = j*128 + wave*16 + fk*4;

  const f32x4 b1q = *(const f32x4*)&b1g[chi];
  const f32x4 b2q = *(const f32x4*)&b2g[chi];

  // ---- resident weights: W1/W2 quarter -> regs (AGPR side), pinned ----
  bf16x8 w1f[16], w2f[16];
  {
    const bf16* p1 = w1g + (size_t)(j*128 + wave*16 + fm)*WIDTH + fk*8;
    const bf16* p2 = w2g + (size_t)(j*128 + wave*16 + fm)*WIDTH + fk*8;
    #pragma unroll
    for (int kk=0; kk<16; kk++) w1f[kk] = *(const bf16x8*)(p1 + kk*32);
    #pragma unroll
    for (int kk=0; kk<16; kk++) w2f[kk] = *(const bf16x8*)(p2 + kk*32);
  }
  // ---- FULL W0 (3 k-steps) + own W3 K-slice -> LDS, fragment order ----
  {
    #pragma unroll
    for (int n=0; n<4; n++){
      const bf16* s0 = w0g + (size_t)((wave*4+n)*16 + fm)*K0 + fk*8;
      #pragma unroll
      for (int k=0; k<3; k++){
        bf16x8 v = *(const bf16x8*)(s0 + k*32);
        *(bf16x8*)&w0s[((wave*4+n)*3 + k)*512 + lane*8] = v;
      }
    }
    const int nt_ = wave & 1, q_ = wave >> 1;
    bf16x8 v3 = *(const bf16x8*)(w3g + (size_t)(nt_*16 + fm)*WIDTH + j*128 + q_*32 + fk*8);
    *(bf16x8*)&w3s[wave*512 + lane*8] = v3;
  }

  // update-phase constants
  const int urow = t >> 5, ucol = t & 31;
  const float b3v = b3g[ucol];
  float* const outp = out + (size_t)(gb0 + urow)*OUTS + ucol;
  const int arow = (t >> 3) & 15, acol = t & 7;
  const float* const actp = actions + (size_t)(gb0 + arow)*(NSTEPS*ACTD) + acol;
  const int swU    = (urow & 15) << 3;
  const int xin_yh = urow*K0 + (ucol ^ swU);
  const int xin_yl = urow*K0 + ((ucol + 32) ^ swU);
  const int xin_ac = arow*K0 + ((64 + acol) ^ ((arow & 15) << 3));

  // ---- init state (y kept in per-thread register; thread-local mapping) ----
  float yreg;
  {
    if (t == 0) sdead = 0;
    #pragma unroll
    for (int q=0; q<(ROWS*K0)/512; q++) xin[q*512 + t] = (bf16)0.0f;
    __syncthreads();
    yreg = init_obs[(gb0 + urow)*OBS + ucol];
    if (j == 0) outp[0] = yreg;
    bf16 yh = (bf16)yreg;
    xin[xin_yh] = yh;
    xin[xin_yl] = (bf16)(yreg - (float)yh);
    if (t < 128) xin[xin_ac] = (bf16)actp[0];
    if (t < 16)  xin[t*K0 + (72 ^ ((t&15)*8))] = (bf16)1.0f;
  }
  __syncthreads();

  // pin resident weights (prevents remat/spill-to-stream; 244 regs = 2 waves/SIMD)
  #pragma unroll
  for (int kk=0; kk<16; kk++){ asm volatile("" : "+v"(w1f[kk])); }
  #pragma unroll
  for (int kk=0; kk<16; kk++){ asm volatile("" : "+v"(w2f[kk])); }

  #define STORE_OWN01(ACC, BQ, HF, HOP) do{ \
    float r0_ = leaky((ACC)[0] + (BQ)[0]); \
    float r1_ = leaky((ACC)[1] + (BQ)[1]); \
    float r2_ = leaky((ACC)[2] + (BQ)[2]); \
    float r3_ = leaky((ACC)[3] + (BQ)[3]); \
    union { u32x2 v; u64 q; } pu_; \
    pu_.v = (u32x2){ pk2(r0_, r1_), pk2(r2_, r3_) }; \
    *(u32x2*)&HF[fm*WIDTH + (chi ^ (fm*8))] = pu_.v; \
    __hip_atomic_store(mbq + (size_t)((g*3+(HOP))*4 + j)*512 + fm*32 + wave*4 + fk, \
                       pu_.q, __ATOMIC_RELAXED, __HIP_MEMORY_SCOPE_AGENT); \
  }while(0)

  #define SYNC_HOP(HOP, ST1) do{ \
    FBAR(); \
    if (t == 0) __hip_atomic_store(flags + ((g*3+(HOP))*4 + j)*16, (ST1), \
                                   __ATOMIC_RELAXED, __HIP_MEMORY_SCOPE_AGENT); \
    if (wave == 0 && lane < 3){ \
      int pm_ = (lane==0)?pm0:((lane==1)?pm1:pm2); \
      const int* fp_ = flags + ((g*3+(HOP))*4 + pm_)*16; \
      int cnt_ = 0; \
      while (!*(volatile int*)&sdead && \
             __hip_atomic_load(fp_, __ATOMIC_RELAXED, __HIP_MEMORY_SCOPE_AGENT) < (ST1)){ \
        __builtin_amdgcn_s_sleep(1); \
        if (++cnt_ > (1<<20)) { *(volatile int*)&sdead = 1; break; } \
      } \
    } \
    LBAR(); \
  }while(0)

  #define GATHER01(HOP, DST) do{ \
    const int br_ = t >> 5, cg_ = t & 31; \
    const size_t hb_ = (size_t)((g*3+(HOP))*4); \
    u64 v0_ = __hip_atomic_load(mbq + (hb_+pm0)*512 + br_*32 + cg_, \
                                 __ATOMIC_RELAXED, __HIP_MEMORY_SCOPE_AGENT); \
    u64 v1_ = __hip_atomic_load(mbq + (hb_+pm1)*512 + br_*32 + cg_, \
                                 __ATOMIC_RELAXED, __HIP_MEMORY_SCOPE_AGENT); \
    u64 v2_ = __hip_atomic_load(mbq + (hb_+pm2)*512 + br_*32 + cg_, \
                                 __ATOMIC_RELAXED, __HIP_MEMORY_SCOPE_AGENT); \
    *(u64*)&DST[br_*WIDTH + ((pm0*128 + cg_*4) ^ (br_*8))] = v0_; \
    *(u64*)&DST[br_*WIDTH + ((pm1*128 + cg_*4) ^ (br_*8))] = v1_; \
    *(u64*)&DST[br_*WIDTH + ((pm2*128 + cg_*4) ^ (br_*8))] = v2_; \
    LBAR(); \
  }while(0)

  #define L2Q(Q) do{ \
    _Pragma("unroll") \
    for (int kk=(Q)*4; kk<(Q)*4+4; kk++){ \
      bf16x8 bb = *(const bf16x8*)&hF1[hbase1 ^ (kk*32)]; \
      acc2 = MFMA_B16(w2f[kk], bb, acc2); \
    } \
  }while(0)

  #define L2MID() do{ \
    if (wave == 0 && lane < 3){ \
      int pm_ = (lane==0)?pm0:((lane==1)?pm1:pm2); \
      const int* fp_ = flags + ((g*3+0)*4 + pm_)*16; \
      int cnt_ = 0; \
      while (!*(volatile int*)&sdead && \
             __hip_atomic_load(fp_, __ATOMIC_RELAXED, __HIP_MEMORY_SCOPE_AGENT) < st1){ \
        __builtin_amdgcn_s_sleep(1); \
        if (++cnt_ > (1<<20)) { *(volatile int*)&sdead = 1; break; } \
      } \
    } \
    LBAR(); \
    GATHER01(0, hF1); \
  }while(0)

  const f32x4 z4 = {0,0,0,0};

  for (int s=0; s<NSTEPS; ++s){
    const int st1 = s + 1;
    const int sidx = (st1 < NSTEPS) ? st1 : 0;
    float av = actp[(size_t)sidx*ACTD];

    // ---- l0 (replicated, full 512 cols): xin @ W0^T, local only ----
    {
      #pragma unroll
      for (int n=0; n<4; n++){
        f32x4 acc = {0,0,0,0};
        #pragma unroll
        for (int k=0; k<3; k++){
          bf16x8 a  = *(const bf16x8*)&w0s[((wave*4+n)*3 + k)*512 + lane*8];
          bf16x8 bb = *(const bf16x8*)&xin[xbase0 ^ (k*32)];
          acc = MFMA_B16(a, bb, acc);
        }
        int ob = (wave*4+n)*16 + fk*4;
        u32x2 pw = { pk2(leaky(acc[0]), leaky(acc[1])),
                     pk2(leaky(acc[2]), leaky(acc[3])) };
        *(u32x2*)&hF0[fm*WIDTH + (ob ^ (fm*8))] = pw;
      }
    }
    LBAR();
    // a(s+1) write: l0(s) has read xin; next xin read is l0(s+1) — off critical tail
    if (t < 128) xin[xin_ac] = (bf16)av;

    // ---- l1: hF0(full h0) @ W1q^T -> own 128 cols, publish (hop 0) ----
    {
      f32x4 acc = {0,0,0,0};
      #pragma unroll
      for (int kk=0; kk<16; kk++){
        bf16x8 bb = *(const bf16x8*)&hF0[hbase1 ^ (kk*32)];
        acc = MFMA_B16(w1f[kk], bb, acc);
      }
      STORE_OWN01(acc, b1q, hF1, 0);
    }
    FBAR();
    if (t == 0) __hip_atomic_store(flags + ((g*3+0)*4 + j)*16, st1,
                                   __ATOMIC_RELAXED, __HIP_MEMORY_SCOPE_AGENT);

    // ---- l2: own-K quarter first (overlaps peers' flag+gather), then rest ----
    f32x4 acc2 = {0,0,0,0};
    switch (j){
      case 0:  L2Q(0); L2MID(); L2Q(1); L2Q(2); L2Q(3); break;
      case 1:  L2Q(1); L2MID(); L2Q(0); L2Q(2); L2Q(3); break;
      case 2:  L2Q(2); L2MID(); L2Q(0); L2Q(1); L2Q(3); break;
      default: L2Q(3); L2MID(); L2Q(0); L2Q(1); L2Q(2); break;
    }
    {
      u32x2 pw = { pk2(leaky(acc2[0]+b2q[0]), leaky(acc2[1]+b2q[1])),
                   pk2(leaky(acc2[2]+b2q[2]), leaky(acc2[3]+b2q[3])) };
      *(u32x2*)&hF0[fm*WIDTH + (chi ^ (fm*8))] = pw;
    }
    LBAR();

    // ---- l3 partial over own 128 K-cols ----
    {
      const int q_ = wave >> 1;
      bf16x8 a  = *(const bf16x8*)&w3s[wave*512 + lane*8];
      bf16x8 bb = *(const bf16x8*)&hF0[fm*WIDTH + ((j*128 + q_*32 + fk*8) ^ (fm*8))];
      f32x4 a3 = MFMA_B16(a, bb, z4);
      *(f32x4*)&pr[wave][fm][fk*4] = a3;
    }
    LBAR();

    // ---- reduce own partials -> mailbox (fp32, 2KB) ----
    float ownv;
    {
      const int ntc = ucol >> 4, c15 = ucol & 15;
      ownv = ((pr[ntc][urow][c15] + pr[2+ntc][urow][c15])
              + pr[4+ntc][urow][c15]) + pr[6+ntc][urow][c15];
      __hip_atomic_store(mbf + (size_t)((g*3+2)*4 + j)*1024 + urow*32 + ucol,
                         ownv, __ATOMIC_RELAXED, __HIP_MEMORY_SCOPE_AGENT);
    }
    SYNC_HOP(2, st1);

    // ---- update: fixed-order member sum -> Euler -> emit -> reseed ----
    {
      float vals[4];
      #pragma unroll
      for (int m=0; m<4; m++){
        if (m == j) vals[m] = ownv;
        else vals[m] = __hip_atomic_load(mbf + (size_t)((g*3+2)*4 + m)*1024 + urow*32 + ucol,
                                         __ATOMIC_RELAXED, __HIP_MEMORY_SCOPE_AGENT);
      }
      float dy = b3v + vals[0] + vals[1] + vals[2] + vals[3];
      float yn = yreg + tauf * dy;
      yreg = yn;
      if (j == 0) outp[(size_t)st1*OBS] = yn;
      bf16 yh = (bf16)yn;
      xin[xin_yh] = yh;
      xin[xin_yl] = (bf16)(yn - (float)yh);
    }
    LBAR();
  }
  asm volatile("s_waitcnt vmcnt(0) lgkmcnt(0)" ::: "memory");
}

extern "C" void kernel_launch(void* const* d_in, const int* in_sizes, int n_in,
                              void* d_out, int out_size, void* d_ws, size_t ws_size,
                              hipStream_t stream){
  const float* init_obs = (const float*)d_in[0];
  const float* actions  = (const float*)d_in[1];
  const float* W0 = (const float*)d_in[2];
  const float* b0 = (const float*)d_in[3];
  const float* W1 = (const float*)d_in[4];
  const float* b1 = (const float*)d_in[5];
  const float* W2 = (const float*)d_in[6];
  const float* b2 = (const float*)d_in[7];
  const float* W3 = (const float*)d_in[8];
  const float* b3 = (const float*)d_in[9];
  const int*  tau = (const int*)d_in[10];
  bf16* wsb = (bf16*)d_ws;
  float* out = (float*)d_out;

  hipLaunchKernelGGL(setup_kernel, dim3(512), dim3(256), 0, stream,
                     W0, b0, W1, W2, W3, tau, wsb);
  hipLaunchKernelGGL(ode_kernel, dim3(256), dim3(512), 0, stream,
                     init_obs, actions, b1, b2, b3, wsb, out);
}